// Round 1
// baseline (1190.759 us; speedup 1.0000x reference)
//
#include <hip/hip_runtime.h>
#include <math.h>

// Problem constants
#define BB 2
#define NDIM 64      // D = H = W = 64
#define CC 128       // channels
#define WR 33        // rfft bins along W
#define NBLK 8
#define BSZ 16

static constexpr float LAM = 0.01f;       // softshrink lambda
static constexpr float ORTHO = 1.0f / 512.0f;  // 1/sqrt(64^3)
static constexpr float TWO_PI_64 = 6.28318530717958647692f / 64.0f;

// LDS row stride (in float2) for one 64-elem transform: pad 64 -> 66 to break
// the 32-way bank conflict of stride-64 float2 columns.
#define LROW 66

__device__ inline float2 cmulf(float2 a, float2 b) {
    return make_float2(a.x * b.x - a.y * b.y, a.x * b.y + a.y * b.x);
}

// Naive fully-unrolled 8-point DFT. DIR = -1 forward, +1 inverse.
// Unrolled loops => T[] indices are compile-time constants => stays in VGPRs.
template <int DIR>
__device__ inline void dft8(const float2 v[8], float2 y[8]) {
    const float s = 0.70710678118654752440f;
    float2 T[8];
    T[0] = make_float2(1.f, 0.f);
    T[1] = make_float2(s, DIR * s);
    T[2] = make_float2(0.f, DIR * 1.f);
    T[3] = make_float2(-s, DIR * s);
    T[4] = make_float2(-1.f, 0.f);
    T[5] = make_float2(-s, -DIR * s);
    T[6] = make_float2(0.f, -DIR * 1.f);
    T[7] = make_float2(s, -DIR * s);
#pragma unroll
    for (int k = 0; k < 8; k++) {
        float2 acc = v[0];
#pragma unroll
        for (int j = 1; j < 8; j++) {
            float2 t = T[(j * k) & 7];
            acc.x += v[j].x * t.x - v[j].y * t.y;
            acc.y += v[j].x * t.y + v[j].y * t.x;
        }
        y[k] = acc;
    }
}

// 64-pt FFT on 64 contiguous float2 in LDS (base), cooperatively by 8 threads
// p = 0..7 of one aligned group (group never straddles a wave).
// Decomposition: X[k1 + 8*k2] = sum_n2 W64^{n2 k1} W8^{n2 k2} sum_n1 x[8 n1 + n2] W8^{n1 k1}
// Caller must __syncthreads() after this before consuming results.
template <int DIR>
__device__ inline void fft64_lds(float2* base, int p) {
    float2 v[8], a[8];
    // stage 1: thread p = n2, reads column {8*n1+p} (its own column)
#pragma unroll
    for (int n1 = 0; n1 < 8; n1++) v[n1] = base[8 * n1 + p];
    dft8<DIR>(v, a);
    // twiddle W64^{DIR * p * k1}
#pragma unroll
    for (int k1 = 1; k1 < 8; k1++) {
        float ang = (float)DIR * TWO_PI_64 * (float)(p * k1);
        float sn, cs;
        __sincosf(ang, &sn, &cs);
        a[k1] = cmulf(a[k1], make_float2(cs, sn));
    }
    // write layout [k1][n2=p] (same column it read: no cross-thread hazard yet)
#pragma unroll
    for (int k1 = 0; k1 < 8; k1++) base[8 * k1 + p] = a[k1];
    __syncthreads();
    // stage 2: thread p = k1, reads row p
    float2 u[8], y[8];
#pragma unroll
    for (int n2 = 0; n2 < 8; n2++) u[n2] = base[8 * p + n2];
    dft8<DIR>(u, y);
    __syncthreads();  // all row-reads done before column writes
#pragma unroll
    for (int k2 = 0; k2 < 8; k2++) base[8 * k2 + p] = y[k2];  // k = p + 8*k2
}

// ---------------- Pass 1: rfft along W. x (B,D,H,W,C) f32 -> buf (B,D,H,WR,C) c64
__global__ __launch_bounds__(256) void k_rfft_w(const float* __restrict__ x,
                                                float2* __restrict__ buf) {
    __shared__ float2 lds[32 * LROW];
    const int t = threadIdx.x;
    const size_t bdh = blockIdx.x;  // 0 .. B*D*H-1
    const float* xp = x + bdh * (size_t)(NDIM * CC);
    float2* op = buf + bdh * (size_t)(WR * CC);
    for (int chunk = 0; chunk < 4; chunk++) {
        const int c0 = chunk * 32;
#pragma unroll
        for (int k = 0; k < 8; k++) {
            int i = k * 256 + t;          // 0..2047
            int c = i & 31, w = i >> 5;   // consecutive lanes -> consecutive c
            float vv = xp[(size_t)w * CC + c0 + c] * ORTHO;
            lds[c * LROW + w] = make_float2(vv, 0.f);
        }
        __syncthreads();
        fft64_lds<-1>(&lds[(t >> 3) * LROW], t & 7);
        __syncthreads();
        for (int i = t; i < WR * 32; i += 256) {
            int c = i & 31, kk = i >> 5;
            op[(size_t)kk * CC + c0 + c] = lds[c * LROW + kk];
        }
        __syncthreads();
    }
}

// ---------------- Passes 2,3,5,6: in-place complex FFT along a strided axis.
// element addr = a*sA + ob*sB + n*sAxis + c   (all in float2 units, c contiguous)
template <int DIR>
__global__ __launch_bounds__(256) void k_fft_axis(float2* __restrict__ buf, int outerB,
                                                  long sA, long sB, long sAxis) {
    __shared__ float2 lds[32 * LROW];
    const int t = threadIdx.x;
    const long a = blockIdx.x / outerB;
    const long ob = blockIdx.x % outerB;
    float2* p0 = buf + a * sA + ob * sB;
    for (int chunk = 0; chunk < 4; chunk++) {
        const int c0 = chunk * 32;
#pragma unroll
        for (int k = 0; k < 8; k++) {
            int i = k * 256 + t;
            int c = i & 31, n = i >> 5;
            lds[c * LROW + n] = p0[(long)n * sAxis + c0 + c];
        }
        __syncthreads();
        fft64_lds<DIR>(&lds[(t >> 3) * LROW], t & 7);
        __syncthreads();
#pragma unroll
        for (int k = 0; k < 8; k++) {
            int i = k * 256 + t;
            int c = i & 31, n = i >> 5;
            p0[(long)n * sAxis + c0 + c] = lds[c * LROW + n];
        }
        __syncthreads();
    }
}

// ---------------- Pass 4: block-diagonal complex MLP + softshrink, in place.
__global__ __launch_bounds__(256) void k_mlp(float2* __restrict__ buf,
                                             const float* __restrict__ w1,
                                             const float* __restrict__ b1,
                                             const float* __restrict__ w2,
                                             const float* __restrict__ b2) {
    __shared__ float sw1r[NBLK * 256], sw1i[NBLK * 256];
    __shared__ float sw2r[NBLK * 256], sw2i[NBLK * 256];
    __shared__ float sb1r[NBLK * BSZ], sb1i[NBLK * BSZ];
    __shared__ float sb2r[NBLK * BSZ], sb2i[NBLK * BSZ];
    const int t = threadIdx.x;
    for (int i = t; i < NBLK * 256; i += 256) {
        sw1r[i] = w1[i];
        sw1i[i] = w1[NBLK * 256 + i];
        sw2r[i] = w2[i];
        sw2i[i] = w2[NBLK * 256 + i];
    }
    for (int i = t; i < NBLK * BSZ; i += 256) {
        sb1r[i] = b1[i];
        sb1i[i] = b1[NBLK * BSZ + i];
        sb2r[i] = b2[i];
        sb2i[i] = b2[NBLK * BSZ + i];
    }
    __syncthreads();
    const long P = (long)BB * NDIM * NDIM * WR;  // 540672 points
    const long J = (long)blockIdx.x * 256 + t;
    if (J >= NBLK * P) return;
    const int blk = (int)(J / P);   // wave-uniform (consecutive J share blk)
    const long pt = J % P;
    float2* bp = buf + pt * CC + blk * BSZ;

    float xr[16], xi[16];
#pragma unroll
    for (int i = 0; i < 16; i++) {
        float2 v = bp[i];
        xr[i] = v.x;
        xi[i] = v.y;
    }
    const float* W1R = &sw1r[blk * 256];
    const float* W1I = &sw1i[blk * 256];
    const float* W2R = &sw2r[blk * 256];
    const float* W2I = &sw2i[blk * 256];

    float o1r[16], o1i[16];
#pragma unroll
    for (int o = 0; o < 16; o++) {
        float sr = sb1r[blk * BSZ + o], si = sb1i[blk * BSZ + o];
#pragma unroll
        for (int i = 0; i < 16; i++) {
            float wr = W1R[i * 16 + o], wi = W1I[i * 16 + o];
            sr += xr[i] * wr - xi[i] * wi;
            si += xi[i] * wr + xr[i] * wi;
        }
        o1r[o] = fmaxf(sr, 0.f);
        o1i[o] = fmaxf(si, 0.f);
    }
#pragma unroll
    for (int o = 0; o < 16; o++) {
        float sr = sb2r[blk * BSZ + o], si = sb2i[blk * BSZ + o];
#pragma unroll
        for (int i = 0; i < 16; i++) {
            float wr = W2R[i * 16 + o], wi = W2I[i * 16 + o];
            sr += o1r[i] * wr - o1i[i] * wi;
            si += o1i[i] * wr + o1r[i] * wi;
        }
        sr = (sr > LAM) ? (sr - LAM) : ((sr < -LAM) ? (sr + LAM) : 0.f);
        si = (si > LAM) ? (si - LAM) : ((si < -LAM) ? (si + LAM) : 0.f);
        bp[o] = make_float2(sr, si);
    }
}

// ---------------- Pass 7: irfft along W (Hermitian reconstruct + inverse c-FFT,
// take real part) * ORTHO + residual x -> out.
__global__ __launch_bounds__(256) void k_irfft_w(const float2* __restrict__ buf,
                                                 const float* __restrict__ x,
                                                 float* __restrict__ out) {
    __shared__ float2 lds[32 * LROW];
    const int t = threadIdx.x;
    const size_t bdh = blockIdx.x;
    const float2* ip = buf + bdh * (size_t)(WR * CC);
    const float* xp = x + bdh * (size_t)(NDIM * CC);
    float* op = out + bdh * (size_t)(NDIM * CC);
    for (int chunk = 0; chunk < 4; chunk++) {
        const int c0 = chunk * 32;
        for (int i = t; i < WR * 32; i += 256) {
            int c = i & 31, kk = i >> 5;
            lds[c * LROW + kk] = ip[(size_t)kk * CC + c0 + c];
        }
        __syncthreads();
        // Hermitian fill: X[64-k] = conj(X[k]) for k=1..31  (writes 33..63, reads 1..31)
        for (int i = t; i < 31 * 32; i += 256) {
            int c = i & 31, kk = 33 + (i >> 5);
            float2 v = lds[c * LROW + (64 - kk)];
            lds[c * LROW + kk] = make_float2(v.x, -v.y);
        }
        __syncthreads();
        fft64_lds<1>(&lds[(t >> 3) * LROW], t & 7);
        __syncthreads();
#pragma unroll
        for (int k = 0; k < 8; k++) {
            int i = k * 256 + t;
            int c = i & 31, w = i >> 5;
            size_t gi = (size_t)w * CC + c0 + c;
            op[gi] = lds[c * LROW + w].x * ORTHO + xp[gi];
        }
        __syncthreads();
    }
}

extern "C" void kernel_launch(void* const* d_in, const int* in_sizes, int n_in,
                              void* d_out, int out_size, void* d_ws, size_t ws_size,
                              hipStream_t stream) {
    const float* x = (const float*)d_in[0];
    const float* w1 = (const float*)d_in[1];
    const float* b1 = (const float*)d_in[2];
    const float* w2 = (const float*)d_in[3];
    const float* b2 = (const float*)d_in[4];
    float* out = (float*)d_out;
    float2* buf = (float2*)d_ws;  // needs B*D*H*WR*C * 8 = 553,648,128 bytes

    const dim3 blk(256);
    // strides in float2 units: c=1, wr=128, h=4224, d=270336, b=17301504
    const long S_WR = CC;                 // 128
    const long S_H = (long)WR * CC;       // 4224
    const long S_D = (long)NDIM * S_H;    // 270336
    const long S_B = (long)NDIM * S_D;    // 17301504

    // 1) rfft along W
    k_rfft_w<<<BB * NDIM * NDIM, blk, 0, stream>>>(x, buf);
    // 2) FFT along H: outerA=(b,d) [128], outerB=wr [33]
    k_fft_axis<-1><<<BB * NDIM * WR, blk, 0, stream>>>(buf, WR, S_D, S_WR, S_H);
    // 3) FFT along D: outerA=b [2], outerB=(h,wr) [2112]
    k_fft_axis<-1><<<BB * NDIM * WR, blk, 0, stream>>>(buf, NDIM * WR, S_B, S_WR, S_D);
    // 4) block-diagonal complex MLP + softshrink (in place)
    {
        const long jobs = (long)NBLK * BB * NDIM * NDIM * WR;  // 4,325,376
        k_mlp<<<(int)((jobs + 255) / 256), blk, 0, stream>>>(buf, w1, b1, w2, b2);
    }
    // 5) inverse FFT along D
    k_fft_axis<1><<<BB * NDIM * WR, blk, 0, stream>>>(buf, NDIM * WR, S_B, S_WR, S_D);
    // 6) inverse FFT along H
    k_fft_axis<1><<<BB * NDIM * WR, blk, 0, stream>>>(buf, WR, S_D, S_WR, S_H);
    // 7) irfft along W + residual
    k_irfft_w<<<BB * NDIM * NDIM, blk, 0, stream>>>(buf, x, out);
}